// Round 2
// baseline (1918.086 us; speedup 1.0000x reference)
//
#include <hip/hip_runtime.h>
#include <math.h>

#define HDIM 128
#define NGAUSS 50
#define NLAYER 6

typedef unsigned short ushortT;
typedef __attribute__((ext_vector_type(8))) short bf16x8;
typedef __attribute__((ext_vector_type(4))) float f32x4;

static __device__ __forceinline__ float bf2f(unsigned short u){
  union { unsigned int i; float f; } x; x.i = ((unsigned int)u) << 16; return x.f;
}
static __device__ __forceinline__ unsigned short f2bf(float f){
  union { float f; unsigned int i; } x; x.f = f;
  unsigned int i = x.i;
  unsigned int r = (i + 0x7FFFu + ((i >> 16) & 1u)) >> 16;
  return (unsigned short)r;
}
// softplus(x) - log(2), numerically stable
static __device__ __forceinline__ float ssp(float x){
  float sp = fmaxf(x, 0.0f) + log1pf(expf(-fabsf(x)));
  return sp - 0.69314718055994530942f;
}

// ---------------- CSR build ----------------
__global__ void k_count(const int* __restrict__ row, int* __restrict__ counts, int E){
  int e = blockIdx.x * 256 + threadIdx.x;
  if (e < E) atomicAdd(&counts[row[e]], 1);
}

__global__ void k_scan(const int* __restrict__ counts, int* __restrict__ offsets,
                       int* __restrict__ cursor, int N){
  __shared__ int sdata[1024];
  int tid = threadIdx.x;
  int chunk = (N + 1023) / 1024;
  int start = tid * chunk;
  int end = start + chunk; if (end > N) end = N;
  int sum = 0;
  for (int i = start; i < end; ++i) sum += counts[i];
  sdata[tid] = sum;
  __syncthreads();
  for (int off = 1; off < 1024; off <<= 1){
    int t = (tid >= off) ? sdata[tid - off] : 0;
    __syncthreads();
    sdata[tid] += t;
    __syncthreads();
  }
  int run = (tid == 0) ? 0 : sdata[tid - 1];
  for (int i = start; i < end; ++i){
    offsets[i] = run; cursor[i] = run;
    run += counts[i];
  }
  if (tid == 0) offsets[N] = sdata[1023];
}

__global__ void k_fill(const int* __restrict__ row, const int* __restrict__ col,
                       const float* __restrict__ pos, int* __restrict__ cursor,
                       int* __restrict__ csr_col, float* __restrict__ csr_dist, int E){
  int e = blockIdx.x * 256 + threadIdx.x;
  if (e >= E) return;
  int r = row[e], c = col[e];
  float dx = pos[r*3+0] - pos[c*3+0];
  float dy = pos[r*3+1] - pos[c*3+1];
  float dz = pos[r*3+2] - pos[c*3+2];
  float d = sqrtf(dx*dx + dy*dy + dz*dz);
  int slot = atomicAdd(&cursor[r], 1);
  csr_col[slot] = c;
  csr_dist[slot] = d;
}

// ---------------- init / precompute ----------------
__global__ void k_init_v(const int* __restrict__ z, const float* __restrict__ emb,
                         ushortT* __restrict__ vhi, ushortT* __restrict__ vlo, int N){
  int idx = blockIdx.x * 256 + threadIdx.x;
  if (idx >= N * HDIM) return;
  int n = idx >> 7, f = idx & 127;
  float w = emb[z[n] * HDIM + f];
  unsigned short hi = f2bf(w);
  vhi[idx] = hi;
  vlo[idx] = f2bf(w - bf2f(hi));
}

// transpose + split weights: dst[mat][n][k] (hi/lo bf16) from src[mat][k][n] (f32)
__global__ void k_prepw(const float* __restrict__ W, ushortT* __restrict__ Whi,
                        ushortT* __restrict__ Wlo, int total){
  int idx = blockIdx.x * 256 + threadIdx.x;
  if (idx >= total) return;
  int mat = idx >> 14;           // / (128*128)
  int rem = idx & 16383;
  int n = rem >> 7, k = rem & 127;
  float w = W[(mat << 14) + k * HDIM + n];
  unsigned short hi = f2bf(w);
  Whi[idx] = hi;
  Wlo[idx] = f2bf(w - bf2f(hi));
}

// a[l][f] = sum_g dist_W[g]*We[l][g][f];  c[l][f] = sum_g dist_b[g]*We[l][g][f] + be[l][f]
__global__ void k_ac(const float* __restrict__ dW, const float* __restrict__ db,
                     const float* __restrict__ We, const float* __restrict__ be,
                     float* __restrict__ a, float* __restrict__ c){
  int idx = blockIdx.x * 256 + threadIdx.x;
  if (idx >= NLAYER * HDIM) return;
  int l = idx >> 7, f = idx & 127;
  float av = 0.f, cv = 0.f;
  for (int g = 0; g < NGAUSS; ++g){
    float we = We[(l * NGAUSS + g) * HDIM + f];
    av += dW[g] * we;
    cv += db[g] * we;
  }
  a[idx] = av;
  c[idx] = cv + be[idx];
}

// ---------------- 128x128 GEMM via MFMA, split precision on A and B ----------------
// WhiT/WloT layout: [n][k] so a B fragment is 8 contiguous bf16.
// MODE 0: out = X @ W            -> outF (f32)
// MODE 1: out = ssp(X @ W + b)   -> outHi/outLo (bf16 hi+lo split)
template<int MODE>
__global__ void k_gemm(const ushortT* __restrict__ Xhi, const ushortT* __restrict__ Xlo,
                       const ushortT* __restrict__ WhiT, const ushortT* __restrict__ WloT,
                       const float* __restrict__ bias,
                       float* __restrict__ outF, ushortT* __restrict__ outHi,
                       ushortT* __restrict__ outLo, int N){
  int wave = threadIdx.x >> 6;
  int lane = threadIdx.x & 63;
  int rowBase = (blockIdx.x * 4 + wave) * 16;
  if (rowBase >= N) return;
  int m = lane & 15;
  int quad = lane >> 4;
  int row = rowBase + m;

  bf16x8 ahi[4], alo[4];
  #pragma unroll
  for (int kk = 0; kk < 4; ++kk){
    ahi[kk] = *(const bf16x8*)(Xhi + (size_t)row * HDIM + kk*32 + quad*8);
    alo[kk] = *(const bf16x8*)(Xlo + (size_t)row * HDIM + kk*32 + quad*8);
  }

  #pragma unroll
  for (int ct = 0; ct < 8; ++ct){
    int ncol = ct * 16 + m;
    f32x4 d = {0.f, 0.f, 0.f, 0.f};
    #pragma unroll
    for (int kk = 0; kk < 4; ++kk){
      bf16x8 bh = *(const bf16x8*)(WhiT + (size_t)ncol * HDIM + kk*32 + quad*8);
      bf16x8 bl = *(const bf16x8*)(WloT + (size_t)ncol * HDIM + kk*32 + quad*8);
      d = __builtin_amdgcn_mfma_f32_16x16x32_bf16(ahi[kk], bh, d, 0, 0, 0);
      d = __builtin_amdgcn_mfma_f32_16x16x32_bf16(ahi[kk], bl, d, 0, 0, 0);
      d = __builtin_amdgcn_mfma_f32_16x16x32_bf16(alo[kk], bh, d, 0, 0, 0);
    }
    #pragma unroll
    for (int r = 0; r < 4; ++r){
      int orow = rowBase + quad*4 + r;
      float val = d[r];
      if (MODE == 0){
        outF[(size_t)orow * HDIM + ncol] = val;
      } else {
        float s = ssp(val + bias[ncol]);
        unsigned short hi = f2bf(s);
        outHi[(size_t)orow * HDIM + ncol] = hi;
        outLo[(size_t)orow * HDIM + ncol] = f2bf(s - bf2f(hi));
      }
    }
  }
}

// ---------------- edge aggregation: one wave per node ----------------
__global__ void k_agg(const float* __restrict__ h, const int* __restrict__ offsets,
                      const int* __restrict__ csr_col, const float* __restrict__ csr_dist,
                      const float* __restrict__ a, const float* __restrict__ c,
                      ushortT* __restrict__ aggHi, ushortT* __restrict__ aggLo, int N){
  int node = blockIdx.x * 4 + (threadIdx.x >> 6);
  if (node >= N) return;
  int lane = threadIdx.x & 63;
  float a0 = a[lane], a1 = a[lane + 64];
  float c0 = c[lane], c1 = c[lane + 64];
  int s = offsets[node], e = offsets[node + 1];
  float acc0 = 0.f, acc1 = 0.f;
  for (int j = s; j < e; ++j){
    int cn = csr_col[j];
    float dd = csr_dist[j];
    const float* hr = h + (size_t)cn * HDIM;
    float w = fmaf(dd, a0, c0);
    float w1 = fmaf(dd, a1, c1);
    acc0 = fmaf(hr[lane],      w,  acc0);
    acc1 = fmaf(hr[lane + 64], w1, acc1);
  }
  size_t o = (size_t)node * HDIM + lane;
  unsigned short h0 = f2bf(acc0), h1 = f2bf(acc1);
  aggHi[o] = h0;       aggHi[o + 64] = h1;
  aggLo[o] = f2bf(acc0 - bf2f(h0));
  aggLo[o + 64] = f2bf(acc1 - bf2f(h1));
}

// ---------------- readout: one wave per node ----------------
__global__ void k_readout(const ushortT* __restrict__ vhi, const ushortT* __restrict__ vlo,
                          const float* __restrict__ W1, const float* __restrict__ b1,
                          const float* __restrict__ W2, const float* __restrict__ b2,
                          const int* __restrict__ batch, float* __restrict__ outAcc, int N){
  int node = blockIdx.x * 4 + (threadIdx.x >> 6);
  if (node >= N) return;
  int lane = threadIdx.x & 63;
  float t = b1[lane];
  const ushortT* vh = vhi + (size_t)node * HDIM;
  const ushortT* vl = vlo + (size_t)node * HDIM;
  #pragma unroll 8
  for (int k = 0; k < HDIM; ++k){
    float v = bf2f(vh[k]) + bf2f(vl[k]);
    t = fmaf(v, W1[k * 64 + lane], t);
  }
  float partial = ssp(t) * W2[lane];
  #pragma unroll
  for (int off = 32; off > 0; off >>= 1)
    partial += __shfl_down(partial, off, 64);
  if (lane == 0)
    atomicAdd(&outAcc[batch[node]], partial + b2[0]);
}

__global__ void k_final(const float* __restrict__ acc, float* __restrict__ out, int G){
  int i = blockIdx.x * 256 + threadIdx.x;
  if (i < G) out[i] = acc[i];
}

extern "C" void kernel_launch(void* const* d_in, const int* in_sizes, int n_in,
                              void* d_out, int out_size, void* d_ws, size_t ws_size,
                              hipStream_t stream){
  const int N = in_sizes[0];
  const int E = in_sizes[3] / 2;
  const int G = out_size;

  const int*   z     = (const int*)d_in[0];
  const float* pos   = (const float*)d_in[1];
  const int*   batch = (const int*)d_in[2];
  const int*   eidx  = (const int*)d_in[3];
  const int*   erow  = eidx;
  const int*   ecol  = eidx + E;
  const float* emb   = (const float*)d_in[4];
  const float* dW    = (const float*)d_in[5];
  const float* db    = (const float*)d_in[6];
  const float* Wn    = (const float*)d_in[7];
  const float* We    = (const float*)d_in[8];
  const float* be    = (const float*)d_in[9];
  const float* Wo    = (const float*)d_in[10];
  const float* bo    = (const float*)d_in[11];
  const float* W1    = (const float*)d_in[12];
  const float* b1    = (const float*)d_in[13];
  const float* W2    = (const float*)d_in[14];
  const float* b2    = (const float*)d_in[15];

  char* ws = (char*)d_ws;
  size_t off = 0;
  auto alloc = [&](size_t bytes) -> char* {
    char* p = ws + off;
    off = (off + bytes + 255) & ~(size_t)255;
    return p;
  };
  int*     counts   = (int*)    alloc((size_t)N * 4);
  int*     offsets  = (int*)    alloc((size_t)(N + 1) * 4);
  int*     cursor   = (int*)    alloc((size_t)N * 4);
  int*     csr_col  = (int*)    alloc((size_t)E * 4);
  float*   csr_dist = (float*)  alloc((size_t)E * 4);
  float*   h        = (float*)  alloc((size_t)N * HDIM * 4);
  ushortT* vhi      = (ushortT*)alloc((size_t)N * HDIM * 2);
  ushortT* vlo      = (ushortT*)alloc((size_t)N * HDIM * 2);
  ushortT* agghi    = (ushortT*)alloc((size_t)N * HDIM * 2);
  ushortT* agglo    = (ushortT*)alloc((size_t)N * HDIM * 2);
  ushortT* WnHiT    = (ushortT*)alloc((size_t)NLAYER * HDIM * HDIM * 2);
  ushortT* WnLoT    = (ushortT*)alloc((size_t)NLAYER * HDIM * HDIM * 2);
  ushortT* WoHiT    = (ushortT*)alloc((size_t)NLAYER * HDIM * HDIM * 2);
  ushortT* WoLoT    = (ushortT*)alloc((size_t)NLAYER * HDIM * HDIM * 2);
  float*   a        = (float*)  alloc((size_t)NLAYER * HDIM * 4);
  float*   c        = (float*)  alloc((size_t)NLAYER * HDIM * 4);
  float*   outAcc   = (float*)  alloc((size_t)G * 4);

  hipMemsetAsync(counts, 0, (size_t)N * 4, stream);
  hipMemsetAsync(outAcc, 0, (size_t)G * 4, stream);

  k_count<<<(E + 255) / 256, 256, 0, stream>>>(erow, counts, E);
  k_scan<<<1, 1024, 0, stream>>>(counts, offsets, cursor, N);
  k_fill<<<(E + 255) / 256, 256, 0, stream>>>(erow, ecol, pos, cursor, csr_col, csr_dist, E);
  k_init_v<<<((size_t)N * HDIM + 255) / 256, 256, 0, stream>>>(z, emb, vhi, vlo, N);
  int wtotal = NLAYER * HDIM * HDIM;
  k_prepw<<<(wtotal + 255) / 256, 256, 0, stream>>>(Wn, WnHiT, WnLoT, wtotal);
  k_prepw<<<(wtotal + 255) / 256, 256, 0, stream>>>(Wo, WoHiT, WoLoT, wtotal);
  k_ac<<<(NLAYER * HDIM + 255) / 256, 256, 0, stream>>>(dW, db, We, be, a, c);

  int gemmGrid = (N + 63) / 64;
  int nodeGrid = (N + 3) / 4;
  for (int l = 0; l < NLAYER; ++l){
    size_t wo = (size_t)l * HDIM * HDIM;
    k_gemm<0><<<gemmGrid, 256, 0, stream>>>(vhi, vlo, WnHiT + wo, WnLoT + wo,
                                            nullptr, h, nullptr, nullptr, N);
    k_agg<<<nodeGrid, 256, 0, stream>>>(h, offsets, csr_col, csr_dist,
                                        a + l * HDIM, c + l * HDIM, agghi, agglo, N);
    k_gemm<1><<<gemmGrid, 256, 0, stream>>>(agghi, agglo, WoHiT + wo, WoLoT + wo,
                                            bo + (size_t)l * HDIM, nullptr, vhi, vlo, N);
  }
  k_readout<<<nodeGrid, 256, 0, stream>>>(vhi, vlo, W1, b1, W2, b2, batch, outAcc, N);
  k_final<<<(G + 255) / 256, 256, 0, stream>>>(outAcc, (float*)d_out, G);
}

// Round 3
// 1347.357 us; speedup vs baseline: 1.4236x; 1.4236x over previous
//
#include <hip/hip_runtime.h>
#include <math.h>

#define HDIM 128
#define NGAUSS 50
#define NLAYER 6

typedef unsigned short ushortT;
typedef __attribute__((ext_vector_type(8))) short bf16x8;
typedef __attribute__((ext_vector_type(4))) float f32x4;

static __device__ __forceinline__ float bf2f(unsigned short u){
  union { unsigned int i; float f; } x; x.i = ((unsigned int)u) << 16; return x.f;
}
static __device__ __forceinline__ unsigned short f2bf(float f){
  union { float f; unsigned int i; } x; x.f = f;
  unsigned int i = x.i;
  unsigned int r = (i + 0x7FFFu + ((i >> 16) & 1u)) >> 16;
  return (unsigned short)r;
}
// softplus(x) - log(2), numerically stable
static __device__ __forceinline__ float ssp(float x){
  float sp = fmaxf(x, 0.0f) + log1pf(expf(-fabsf(x)));
  return sp - 0.69314718055994530942f;
}

// ---------------- CSR build ----------------
__global__ void k_count(const int* __restrict__ row, int* __restrict__ counts, int E){
  int e = blockIdx.x * 256 + threadIdx.x;
  if (e < E) atomicAdd(&counts[row[e]], 1);
}

__global__ void k_scan(const int* __restrict__ counts, int* __restrict__ offsets,
                       int* __restrict__ cursor, int N){
  __shared__ int sdata[1024];
  int tid = threadIdx.x;
  int chunk = (N + 1023) / 1024;
  int start = tid * chunk;
  int end = start + chunk; if (end > N) end = N;
  int sum = 0;
  for (int i = start; i < end; ++i) sum += counts[i];
  sdata[tid] = sum;
  __syncthreads();
  for (int off = 1; off < 1024; off <<= 1){
    int t = (tid >= off) ? sdata[tid - off] : 0;
    __syncthreads();
    sdata[tid] += t;
    __syncthreads();
  }
  int run = (tid == 0) ? 0 : sdata[tid - 1];
  for (int i = start; i < end; ++i){
    offsets[i] = run; cursor[i] = run;
    run += counts[i];
  }
  if (tid == 0) offsets[N] = sdata[1023];
}

// csr record: (col, dist-bits) packed as int2 -> one 8B store, one 8B load
__global__ void k_fill(const int* __restrict__ row, const int* __restrict__ col,
                       const float* __restrict__ pos, int* __restrict__ cursor,
                       int2* __restrict__ csr_cd, int E){
  int e = blockIdx.x * 256 + threadIdx.x;
  if (e >= E) return;
  int r = row[e], c = col[e];
  float dx = pos[r*3+0] - pos[c*3+0];
  float dy = pos[r*3+1] - pos[c*3+1];
  float dz = pos[r*3+2] - pos[c*3+2];
  float d = sqrtf(dx*dx + dy*dy + dz*dz);
  int slot = atomicAdd(&cursor[r], 1);
  csr_cd[slot] = make_int2(c, __float_as_int(d));
}

// ---------------- init / precompute ----------------
__global__ void k_init_v(const int* __restrict__ z, const float* __restrict__ emb,
                         ushortT* __restrict__ vhi, ushortT* __restrict__ vlo, int N){
  int idx = blockIdx.x * 256 + threadIdx.x;
  if (idx >= N * HDIM) return;
  int n = idx >> 7, f = idx & 127;
  float w = emb[z[n] * HDIM + f];
  unsigned short hi = f2bf(w);
  vhi[idx] = hi;
  vlo[idx] = f2bf(w - bf2f(hi));
}

// transpose + split weights: dst[mat][n][k] (hi/lo bf16) from src[mat][k][n] (f32)
__global__ void k_prepw(const float* __restrict__ W, ushortT* __restrict__ Whi,
                        ushortT* __restrict__ Wlo, int total){
  int idx = blockIdx.x * 256 + threadIdx.x;
  if (idx >= total) return;
  int mat = idx >> 14;           // / (128*128)
  int rem = idx & 16383;
  int n = rem >> 7, k = rem & 127;
  float w = W[(mat << 14) + k * HDIM + n];
  unsigned short hi = f2bf(w);
  Whi[idx] = hi;
  Wlo[idx] = f2bf(w - bf2f(hi));
}

// a[l][f] = sum_g dist_W[g]*We[l][g][f];  c[l][f] = sum_g dist_b[g]*We[l][g][f] + be[l][f]
__global__ void k_ac(const float* __restrict__ dW, const float* __restrict__ db,
                     const float* __restrict__ We, const float* __restrict__ be,
                     float* __restrict__ a, float* __restrict__ c){
  int idx = blockIdx.x * 256 + threadIdx.x;
  if (idx >= NLAYER * HDIM) return;
  int l = idx >> 7, f = idx & 127;
  float av = 0.f, cv = 0.f;
  for (int g = 0; g < NGAUSS; ++g){
    float we = We[(l * NGAUSS + g) * HDIM + f];
    av += dW[g] * we;
    cv += db[g] * we;
  }
  a[idx] = av;
  c[idx] = cv + be[idx];
}

// ---------------- 128x128 GEMM via MFMA, split precision, LDS-staged weights ----
// Weights staged in exactly 64KB LDS with k-rotation swizzle (no padding):
//   lds[n*128 + ((k + 8*(n&15)) & 127)]  -- keeps 16B fragments contiguous,
//   spreads the 16 ncol rows of a fragment read across bank groups.
// MODE 0: out = X @ W             -> outHi (bf16, hi only; feeds the gather)
// MODE 1: out = ssp(X @ W + b)    -> outHi/outLo (bf16 hi+lo split)
template<int MODE>
__global__ __launch_bounds__(256, 2)
void k_gemm(const ushortT* __restrict__ Xhi, const ushortT* __restrict__ Xlo,
            const ushortT* __restrict__ WhiT, const ushortT* __restrict__ WloT,
            const float* __restrict__ bias,
            ushortT* __restrict__ outHi, ushortT* __restrict__ outLo, int N){
  __shared__ ushortT lds[2 * 128 * 128];   // 64 KB exactly
  ushortT* lh = lds;
  ushortT* ll = lds + 128 * 128;
  int tid = threadIdx.x;
  #pragma unroll
  for (int i = 0; i < 8; ++i){
    int g = (i * 256 + tid) * 8;          // short index 0..16383, 8 contiguous
    int n = g >> 7, k = g & 127;
    int dst = n * 128 + ((k + 8 * (n & 15)) & 127);
    *(bf16x8*)(lh + dst) = *(const bf16x8*)(WhiT + g);
    *(bf16x8*)(ll + dst) = *(const bf16x8*)(WloT + g);
  }
  __syncthreads();

  int wave = tid >> 6, lane = tid & 63;
  int m = lane & 15, quad = lane >> 4;
  int ntiles = (N + 15) >> 4;
  for (int tile = blockIdx.x * 4 + wave; tile < ntiles; tile += gridDim.x * 4){
    int rowBase = tile << 4;
    int row = rowBase + m; if (row >= N) row = N - 1;
    bf16x8 ahi[4], alo[4];
    #pragma unroll
    for (int kk = 0; kk < 4; ++kk){
      ahi[kk] = *(const bf16x8*)(Xhi + ((size_t)row << 7) + kk*32 + quad*8);
      alo[kk] = *(const bf16x8*)(Xlo + ((size_t)row << 7) + kk*32 + quad*8);
    }
    #pragma unroll
    for (int ct = 0; ct < 8; ++ct){
      int ncol = ct * 16 + m;
      f32x4 d = {0.f, 0.f, 0.f, 0.f};
      #pragma unroll
      for (int kk = 0; kk < 4; ++kk){
        int koff = (kk*32 + quad*8 + 8*m) & 127;
        bf16x8 bh = *(const bf16x8*)(lh + ncol*128 + koff);
        bf16x8 bl = *(const bf16x8*)(ll + ncol*128 + koff);
        d = __builtin_amdgcn_mfma_f32_16x16x32_bf16(ahi[kk], bh, d, 0, 0, 0);
        d = __builtin_amdgcn_mfma_f32_16x16x32_bf16(ahi[kk], bl, d, 0, 0, 0);
        d = __builtin_amdgcn_mfma_f32_16x16x32_bf16(alo[kk], bh, d, 0, 0, 0);
      }
      #pragma unroll
      for (int r = 0; r < 4; ++r){
        int orow = rowBase + quad*4 + r;
        if (orow < N){
          if (MODE == 0){
            outHi[((size_t)orow << 7) + ncol] = f2bf(d[r]);
          } else {
            float s = ssp(d[r] + bias[ncol]);
            unsigned short hi = f2bf(s);
            outHi[((size_t)orow << 7) + ncol] = hi;
            outLo[((size_t)orow << 7) + ncol] = f2bf(s - bf2f(hi));
          }
        }
      }
    }
  }
}

// ---------------- edge aggregation: one wave per node, bf16 h, 4-edge unroll ----
__global__ void k_agg(const ushortT* __restrict__ h, const int* __restrict__ offsets,
                      const int2* __restrict__ cd, const float* __restrict__ a,
                      const float* __restrict__ c,
                      ushortT* __restrict__ aggHi, ushortT* __restrict__ aggLo, int N){
  int node = blockIdx.x * 4 + (threadIdx.x >> 6);
  if (node >= N) return;
  int lane = threadIdx.x & 63;
  int f = lane * 2;                       // this lane covers features f, f+1
  float a0 = a[f], a1 = a[f+1], c0 = c[f], c1 = c[f+1];
  int s = offsets[node], e = offsets[node + 1];
  float acc0 = 0.f, acc1 = 0.f;
  int j = s;
  for (; j + 4 <= e; j += 4){
    int2 q0 = cd[j], q1 = cd[j+1], q2 = cd[j+2], q3 = cd[j+3];
    unsigned int p0 = *(const unsigned int*)(h + ((size_t)q0.x << 7) + f);
    unsigned int p1 = *(const unsigned int*)(h + ((size_t)q1.x << 7) + f);
    unsigned int p2 = *(const unsigned int*)(h + ((size_t)q2.x << 7) + f);
    unsigned int p3 = *(const unsigned int*)(h + ((size_t)q3.x << 7) + f);
    float d0 = __int_as_float(q0.y), d1 = __int_as_float(q1.y);
    float d2 = __int_as_float(q2.y), d3 = __int_as_float(q3.y);
    acc0 = fmaf(bf2f((ushortT)p0),        fmaf(d0, a0, c0), acc0);
    acc1 = fmaf(bf2f((ushortT)(p0 >> 16)), fmaf(d0, a1, c1), acc1);
    acc0 = fmaf(bf2f((ushortT)p1),        fmaf(d1, a0, c0), acc0);
    acc1 = fmaf(bf2f((ushortT)(p1 >> 16)), fmaf(d1, a1, c1), acc1);
    acc0 = fmaf(bf2f((ushortT)p2),        fmaf(d2, a0, c0), acc0);
    acc1 = fmaf(bf2f((ushortT)(p2 >> 16)), fmaf(d2, a1, c1), acc1);
    acc0 = fmaf(bf2f((ushortT)p3),        fmaf(d3, a0, c0), acc0);
    acc1 = fmaf(bf2f((ushortT)(p3 >> 16)), fmaf(d3, a1, c1), acc1);
  }
  for (; j < e; ++j){
    int2 q = cd[j];
    unsigned int p = *(const unsigned int*)(h + ((size_t)q.x << 7) + f);
    float dd = __int_as_float(q.y);
    acc0 = fmaf(bf2f((ushortT)p),        fmaf(dd, a0, c0), acc0);
    acc1 = fmaf(bf2f((ushortT)(p >> 16)), fmaf(dd, a1, c1), acc1);
  }
  unsigned short h0 = f2bf(acc0), h1 = f2bf(acc1);
  size_t o = ((size_t)node << 7) + f;
  *(unsigned int*)(aggHi + o) = (unsigned int)h0 | ((unsigned int)h1 << 16);
  unsigned short l0 = f2bf(acc0 - bf2f(h0)), l1 = f2bf(acc1 - bf2f(h1));
  *(unsigned int*)(aggLo + o) = (unsigned int)l0 | ((unsigned int)l1 << 16);
}

// ---------------- readout: one wave per node, LDS-staged v ----------------
__global__ void k_readout(const ushortT* __restrict__ vhi, const ushortT* __restrict__ vlo,
                          const float* __restrict__ W1, const float* __restrict__ b1,
                          const float* __restrict__ W2, const float* __restrict__ b2,
                          const int* __restrict__ batch, float* __restrict__ outAcc, int N){
  __shared__ float vbuf[4][HDIM];
  int wave = threadIdx.x >> 6, lane = threadIdx.x & 63;
  int node = blockIdx.x * 4 + wave;
  if (node >= N) return;
  int f = lane * 2;
  unsigned int hh = *(const unsigned int*)(vhi + ((size_t)node << 7) + f);
  unsigned int ll = *(const unsigned int*)(vlo + ((size_t)node << 7) + f);
  vbuf[wave][f]     = bf2f((ushortT)hh)         + bf2f((ushortT)ll);
  vbuf[wave][f + 1] = bf2f((ushortT)(hh >> 16)) + bf2f((ushortT)(ll >> 16));
  // wave-local LDS write->read: compiler orders via lgkmcnt (same array dep)
  float t = b1[lane];
  #pragma unroll 8
  for (int k = 0; k < HDIM; ++k)
    t = fmaf(vbuf[wave][k], W1[k * 64 + lane], t);
  float partial = ssp(t) * W2[lane];
  #pragma unroll
  for (int off = 32; off > 0; off >>= 1)
    partial += __shfl_down(partial, off, 64);
  if (lane == 0)
    atomicAdd(&outAcc[batch[node]], partial + b2[0]);
}

__global__ void k_final(const float* __restrict__ acc, float* __restrict__ out, int G){
  int i = blockIdx.x * 256 + threadIdx.x;
  if (i < G) out[i] = acc[i];
}

extern "C" void kernel_launch(void* const* d_in, const int* in_sizes, int n_in,
                              void* d_out, int out_size, void* d_ws, size_t ws_size,
                              hipStream_t stream){
  const int N = in_sizes[0];
  const int E = in_sizes[3] / 2;
  const int G = out_size;

  const int*   z     = (const int*)d_in[0];
  const float* pos   = (const float*)d_in[1];
  const int*   batch = (const int*)d_in[2];
  const int*   eidx  = (const int*)d_in[3];
  const int*   erow  = eidx;
  const int*   ecol  = eidx + E;
  const float* emb   = (const float*)d_in[4];
  const float* dW    = (const float*)d_in[5];
  const float* db    = (const float*)d_in[6];
  const float* Wn    = (const float*)d_in[7];
  const float* We    = (const float*)d_in[8];
  const float* be    = (const float*)d_in[9];
  const float* Wo    = (const float*)d_in[10];
  const float* bo    = (const float*)d_in[11];
  const float* W1    = (const float*)d_in[12];
  const float* b1    = (const float*)d_in[13];
  const float* W2    = (const float*)d_in[14];
  const float* b2    = (const float*)d_in[15];

  char* ws = (char*)d_ws;
  size_t off = 0;
  auto alloc = [&](size_t bytes) -> char* {
    char* p = ws + off;
    off = (off + bytes + 255) & ~(size_t)255;
    return p;
  };
  int*     counts   = (int*)    alloc((size_t)N * 4);
  int*     offsets  = (int*)    alloc((size_t)(N + 1) * 4);
  int*     cursor   = (int*)    alloc((size_t)N * 4);
  int2*    csr_cd   = (int2*)   alloc((size_t)E * 8);
  ushortT* h        = (ushortT*)alloc((size_t)N * HDIM * 2);
  ushortT* vhi      = (ushortT*)alloc((size_t)N * HDIM * 2);
  ushortT* vlo      = (ushortT*)alloc((size_t)N * HDIM * 2);
  ushortT* agghi    = (ushortT*)alloc((size_t)N * HDIM * 2);
  ushortT* agglo    = (ushortT*)alloc((size_t)N * HDIM * 2);
  ushortT* WnHiT    = (ushortT*)alloc((size_t)NLAYER * HDIM * HDIM * 2);
  ushortT* WnLoT    = (ushortT*)alloc((size_t)NLAYER * HDIM * HDIM * 2);
  ushortT* WoHiT    = (ushortT*)alloc((size_t)NLAYER * HDIM * HDIM * 2);
  ushortT* WoLoT    = (ushortT*)alloc((size_t)NLAYER * HDIM * HDIM * 2);
  float*   a        = (float*)  alloc((size_t)NLAYER * HDIM * 4);
  float*   c        = (float*)  alloc((size_t)NLAYER * HDIM * 4);
  float*   outAcc   = (float*)  alloc((size_t)G * 4);

  hipMemsetAsync(counts, 0, (size_t)N * 4, stream);
  hipMemsetAsync(outAcc, 0, (size_t)G * 4, stream);

  k_count<<<(E + 255) / 256, 256, 0, stream>>>(erow, counts, E);
  k_scan<<<1, 1024, 0, stream>>>(counts, offsets, cursor, N);
  k_fill<<<(E + 255) / 256, 256, 0, stream>>>(erow, ecol, pos, cursor, csr_cd, E);
  k_init_v<<<((size_t)N * HDIM + 255) / 256, 256, 0, stream>>>(z, emb, vhi, vlo, N);
  int wtotal = NLAYER * HDIM * HDIM;
  k_prepw<<<(wtotal + 255) / 256, 256, 0, stream>>>(Wn, WnHiT, WnLoT, wtotal);
  k_prepw<<<(wtotal + 255) / 256, 256, 0, stream>>>(Wo, WoHiT, WoLoT, wtotal);
  k_ac<<<(NLAYER * HDIM + 255) / 256, 256, 0, stream>>>(dW, db, We, be, a, c);

  // grid sized so the 3125 row-tiles split into exactly 2 per wave
  int ntiles = (N + 15) >> 4;
  int gemmGrid = (ntiles + 7) / 8;        // 4 waves/block, 2 tiles/wave
  int nodeGrid = (N + 3) / 4;
  for (int l = 0; l < NLAYER; ++l){
    size_t wo = (size_t)l * HDIM * HDIM;
    k_gemm<0><<<gemmGrid, 256, 0, stream>>>(vhi, vlo, WnHiT + wo, WnLoT + wo,
                                            nullptr, h, nullptr, N);
    k_agg<<<nodeGrid, 256, 0, stream>>>(h, offsets, csr_cd,
                                        a + l * HDIM, c + l * HDIM, agghi, agglo, N);
    k_gemm<1><<<gemmGrid, 256, 0, stream>>>(agghi, agglo, WoHiT + wo, WoLoT + wo,
                                            bo + (size_t)l * HDIM, vhi, vlo, N);
  }
  k_readout<<<nodeGrid, 256, 0, stream>>>(vhi, vlo, W1, b1, W2, b2, batch, outAcc, N);
  k_final<<<(G + 255) / 256, 256, 0, stream>>>(outAcc, (float*)d_out, G);
}

// Round 4
// 1263.487 us; speedup vs baseline: 1.5181x; 1.0664x over previous
//
#include <hip/hip_runtime.h>
#include <math.h>

#define HDIM 128
#define NGAUSS 50
#define NLAYER 6

typedef unsigned short ushortT;
typedef __attribute__((ext_vector_type(8))) short bf16x8;
typedef __attribute__((ext_vector_type(4))) float f32x4;

static __device__ __forceinline__ float bf2f(unsigned short u){
  union { unsigned int i; float f; } x; x.i = ((unsigned int)u) << 16; return x.f;
}
static __device__ __forceinline__ unsigned short f2bf(float f){
  union { float f; unsigned int i; } x; x.f = f;
  unsigned int i = x.i;
  unsigned int r = (i + 0x7FFFu + ((i >> 16) & 1u)) >> 16;
  return (unsigned short)r;
}
// softplus(x) - log(2), numerically stable
static __device__ __forceinline__ float ssp(float x){
  float sp = fmaxf(x, 0.0f) + log1pf(expf(-fabsf(x)));
  return sp - 0.69314718055994530942f;
}

// ---------------- CSR build ----------------
__global__ void k_count(const int* __restrict__ row, int* __restrict__ counts, int E){
  int e = blockIdx.x * 256 + threadIdx.x;
  if (e < E) atomicAdd(&counts[row[e]], 1);
}

__global__ void k_scan(const int* __restrict__ counts, int* __restrict__ offsets,
                       int* __restrict__ cursor, int N){
  __shared__ int sdata[1024];
  int tid = threadIdx.x;
  int chunk = (N + 1023) / 1024;
  int start = tid * chunk;
  int end = start + chunk; if (end > N) end = N;
  int sum = 0;
  for (int i = start; i < end; ++i) sum += counts[i];
  sdata[tid] = sum;
  __syncthreads();
  for (int off = 1; off < 1024; off <<= 1){
    int t = (tid >= off) ? sdata[tid - off] : 0;
    __syncthreads();
    sdata[tid] += t;
    __syncthreads();
  }
  int run = (tid == 0) ? 0 : sdata[tid - 1];
  for (int i = start; i < end; ++i){
    offsets[i] = run; cursor[i] = run;
    run += counts[i];
  }
  if (tid == 0) offsets[N] = sdata[1023];
}

// csr record: (col, dist-bits) packed as int2 -> one 8B store, one 8B load
__global__ void k_fill(const int* __restrict__ row, const int* __restrict__ col,
                       const float* __restrict__ pos, int* __restrict__ cursor,
                       int2* __restrict__ csr_cd, int E){
  int e = blockIdx.x * 256 + threadIdx.x;
  if (e >= E) return;
  int r = row[e], c = col[e];
  float dx = pos[r*3+0] - pos[c*3+0];
  float dy = pos[r*3+1] - pos[c*3+1];
  float dz = pos[r*3+2] - pos[c*3+2];
  float d = sqrtf(dx*dx + dy*dy + dz*dz);
  int slot = atomicAdd(&cursor[r], 1);
  csr_cd[slot] = make_int2(c, __float_as_int(d));
}

// ---------------- init / precompute ----------------
__global__ void k_init_v(const int* __restrict__ z, const float* __restrict__ emb,
                         ushortT* __restrict__ vhi, ushortT* __restrict__ vlo, int N){
  int idx = blockIdx.x * 256 + threadIdx.x;
  if (idx >= N * HDIM) return;
  int n = idx >> 7, f = idx & 127;
  float w = emb[z[n] * HDIM + f];
  unsigned short hi = f2bf(w);
  vhi[idx] = hi;
  vlo[idx] = f2bf(w - bf2f(hi));
}

// transpose + split weights: dst[mat][n][k] (hi/lo bf16) from src[mat][k][n] (f32)
__global__ void k_prepw(const float* __restrict__ W, ushortT* __restrict__ Whi,
                        ushortT* __restrict__ Wlo, int total){
  int idx = blockIdx.x * 256 + threadIdx.x;
  if (idx >= total) return;
  int mat = idx >> 14;           // / (128*128)
  int rem = idx & 16383;
  int n = rem >> 7, k = rem & 127;
  float w = W[(mat << 14) + k * HDIM + n];
  unsigned short hi = f2bf(w);
  Whi[idx] = hi;
  Wlo[idx] = f2bf(w - bf2f(hi));
}

// a[l][f] = sum_g dist_W[g]*We[l][g][f];  c[l][f] = sum_g dist_b[g]*We[l][g][f] + be[l][f]
__global__ void k_ac(const float* __restrict__ dW, const float* __restrict__ db,
                     const float* __restrict__ We, const float* __restrict__ be,
                     float* __restrict__ a, float* __restrict__ c){
  int idx = blockIdx.x * 256 + threadIdx.x;
  if (idx >= NLAYER * HDIM) return;
  int l = idx >> 7, f = idx & 127;
  float av = 0.f, cv = 0.f;
  for (int g = 0; g < NGAUSS; ++g){
    float we = We[(l * NGAUSS + g) * HDIM + f];
    av += dW[g] * we;
    cv += db[g] * we;
  }
  a[idx] = av;
  c[idx] = cv + be[idx];
}

// ---------------- 128x128 GEMM via MFMA, split precision, LDS-staged weights ----
// MODE 0: out = X @ W             -> outHi (bf16, hi only; feeds the gather)
// MODE 1: out = ssp(X @ W + b)    -> outHi/outLo (bf16 hi+lo split)
template<int MODE>
__global__ __launch_bounds__(256, 2)
void k_gemm(const ushortT* __restrict__ Xhi, const ushortT* __restrict__ Xlo,
            const ushortT* __restrict__ WhiT, const ushortT* __restrict__ WloT,
            const float* __restrict__ bias,
            ushortT* __restrict__ outHi, ushortT* __restrict__ outLo, int N){
  __shared__ ushortT lds[2 * 128 * 128];   // 64 KB exactly
  ushortT* lh = lds;
  ushortT* ll = lds + 128 * 128;
  int tid = threadIdx.x;
  #pragma unroll
  for (int i = 0; i < 8; ++i){
    int g = (i * 256 + tid) * 8;          // short index 0..16383, 8 contiguous
    int n = g >> 7, k = g & 127;
    int dst = n * 128 + ((k + 8 * (n & 15)) & 127);
    *(bf16x8*)(lh + dst) = *(const bf16x8*)(WhiT + g);
    *(bf16x8*)(ll + dst) = *(const bf16x8*)(WloT + g);
  }
  __syncthreads();

  int wave = tid >> 6, lane = tid & 63;
  int m = lane & 15, quad = lane >> 4;
  int ntiles = (N + 15) >> 4;
  for (int tile = blockIdx.x * 4 + wave; tile < ntiles; tile += gridDim.x * 4){
    int rowBase = tile << 4;
    int row = rowBase + m; if (row >= N) row = N - 1;
    bf16x8 ahi[4], alo[4];
    #pragma unroll
    for (int kk = 0; kk < 4; ++kk){
      ahi[kk] = *(const bf16x8*)(Xhi + ((size_t)row << 7) + kk*32 + quad*8);
      alo[kk] = *(const bf16x8*)(Xlo + ((size_t)row << 7) + kk*32 + quad*8);
    }
    #pragma unroll
    for (int ct = 0; ct < 8; ++ct){
      int ncol = ct * 16 + m;
      f32x4 d = {0.f, 0.f, 0.f, 0.f};
      #pragma unroll
      for (int kk = 0; kk < 4; ++kk){
        int koff = (kk*32 + quad*8 + 8*m) & 127;
        bf16x8 bh = *(const bf16x8*)(lh + ncol*128 + koff);
        bf16x8 bl = *(const bf16x8*)(ll + ncol*128 + koff);
        d = __builtin_amdgcn_mfma_f32_16x16x32_bf16(ahi[kk], bh, d, 0, 0, 0);
        d = __builtin_amdgcn_mfma_f32_16x16x32_bf16(ahi[kk], bl, d, 0, 0, 0);
        d = __builtin_amdgcn_mfma_f32_16x16x32_bf16(alo[kk], bh, d, 0, 0, 0);
      }
      #pragma unroll
      for (int r = 0; r < 4; ++r){
        int orow = rowBase + quad*4 + r;
        if (orow < N){
          if (MODE == 0){
            outHi[((size_t)orow << 7) + ncol] = f2bf(d[r]);
          } else {
            float s = ssp(d[r] + bias[ncol]);
            unsigned short hi = f2bf(s);
            outHi[((size_t)orow << 7) + ncol] = hi;
            outLo[((size_t)orow << 7) + ncol] = f2bf(s - bf2f(hi));
          }
        }
      }
    }
  }
}

// ---------------- edge aggregation: one wave per node, bf16 h, 8-edge MLP ----
__global__ void k_agg(const ushortT* __restrict__ h, const int* __restrict__ offsets,
                      const int2* __restrict__ cd, const float* __restrict__ a,
                      const float* __restrict__ c,
                      ushortT* __restrict__ aggHi, ushortT* __restrict__ aggLo, int N){
  int node = blockIdx.x * 4 + (threadIdx.x >> 6);
  if (node >= N) return;
  int lane = threadIdx.x & 63;
  int f = lane * 2;                       // this lane covers features f, f+1
  float a0 = a[f], a1 = a[f+1], c0 = c[f], c1 = c[f+1];
  int s = offsets[node], e = offsets[node + 1];
  float acc0 = 0.f, acc1 = 0.f;
  int j = s;
  // peel one edge if start is odd so int4 loads below are 16B-aligned
  if ((j & 1) && j < e){
    int2 q = cd[j];
    unsigned int p = *(const unsigned int*)(h + ((size_t)q.x << 7) + f);
    float dd = __int_as_float(q.y);
    acc0 = fmaf(bf2f((ushortT)p),          fmaf(dd, a0, c0), acc0);
    acc1 = fmaf(bf2f((ushortT)(p >> 16)),  fmaf(dd, a1, c1), acc1);
    ++j;
  }
  for (; j + 8 <= e; j += 8){
    int4 qa = *(const int4*)(cd + j);       // edges j, j+1
    int4 qb = *(const int4*)(cd + j + 2);
    int4 qc = *(const int4*)(cd + j + 4);
    int4 qd = *(const int4*)(cd + j + 6);
    unsigned int p0 = *(const unsigned int*)(h + ((size_t)qa.x << 7) + f);
    unsigned int p1 = *(const unsigned int*)(h + ((size_t)qa.z << 7) + f);
    unsigned int p2 = *(const unsigned int*)(h + ((size_t)qb.x << 7) + f);
    unsigned int p3 = *(const unsigned int*)(h + ((size_t)qb.z << 7) + f);
    unsigned int p4 = *(const unsigned int*)(h + ((size_t)qc.x << 7) + f);
    unsigned int p5 = *(const unsigned int*)(h + ((size_t)qc.z << 7) + f);
    unsigned int p6 = *(const unsigned int*)(h + ((size_t)qd.x << 7) + f);
    unsigned int p7 = *(const unsigned int*)(h + ((size_t)qd.z << 7) + f);
    float d0 = __int_as_float(qa.y), d1 = __int_as_float(qa.w);
    float d2 = __int_as_float(qb.y), d3 = __int_as_float(qb.w);
    float d4 = __int_as_float(qc.y), d5 = __int_as_float(qc.w);
    float d6 = __int_as_float(qd.y), d7 = __int_as_float(qd.w);
    acc0 = fmaf(bf2f((ushortT)p0),         fmaf(d0, a0, c0), acc0);
    acc1 = fmaf(bf2f((ushortT)(p0 >> 16)), fmaf(d0, a1, c1), acc1);
    acc0 = fmaf(bf2f((ushortT)p1),         fmaf(d1, a0, c0), acc0);
    acc1 = fmaf(bf2f((ushortT)(p1 >> 16)), fmaf(d1, a1, c1), acc1);
    acc0 = fmaf(bf2f((ushortT)p2),         fmaf(d2, a0, c0), acc0);
    acc1 = fmaf(bf2f((ushortT)(p2 >> 16)), fmaf(d2, a1, c1), acc1);
    acc0 = fmaf(bf2f((ushortT)p3),         fmaf(d3, a0, c0), acc0);
    acc1 = fmaf(bf2f((ushortT)(p3 >> 16)), fmaf(d3, a1, c1), acc1);
    acc0 = fmaf(bf2f((ushortT)p4),         fmaf(d4, a0, c0), acc0);
    acc1 = fmaf(bf2f((ushortT)(p4 >> 16)), fmaf(d4, a1, c1), acc1);
    acc0 = fmaf(bf2f((ushortT)p5),         fmaf(d5, a0, c0), acc0);
    acc1 = fmaf(bf2f((ushortT)(p5 >> 16)), fmaf(d5, a1, c1), acc1);
    acc0 = fmaf(bf2f((ushortT)p6),         fmaf(d6, a0, c0), acc0);
    acc1 = fmaf(bf2f((ushortT)(p6 >> 16)), fmaf(d6, a1, c1), acc1);
    acc0 = fmaf(bf2f((ushortT)p7),         fmaf(d7, a0, c0), acc0);
    acc1 = fmaf(bf2f((ushortT)(p7 >> 16)), fmaf(d7, a1, c1), acc1);
  }
  for (; j < e; ++j){
    int2 q = cd[j];
    unsigned int p = *(const unsigned int*)(h + ((size_t)q.x << 7) + f);
    float dd = __int_as_float(q.y);
    acc0 = fmaf(bf2f((ushortT)p),         fmaf(dd, a0, c0), acc0);
    acc1 = fmaf(bf2f((ushortT)(p >> 16)), fmaf(dd, a1, c1), acc1);
  }
  unsigned short h0 = f2bf(acc0), h1 = f2bf(acc1);
  size_t o = ((size_t)node << 7) + f;
  *(unsigned int*)(aggHi + o) = (unsigned int)h0 | ((unsigned int)h1 << 16);
  unsigned short l0 = f2bf(acc0 - bf2f(h0)), l1 = f2bf(acc1 - bf2f(h1));
  *(unsigned int*)(aggLo + o) = (unsigned int)l0 | ((unsigned int)l1 << 16);
}

// ---------------- readout: one wave per node, writes u[node] (no atomics) ----
__global__ void k_readout(const ushortT* __restrict__ vhi, const ushortT* __restrict__ vlo,
                          const float* __restrict__ W1, const float* __restrict__ b1,
                          const float* __restrict__ W2, const float* __restrict__ b2,
                          float* __restrict__ u, int N){
  __shared__ float vbuf[4][HDIM];
  int wave = threadIdx.x >> 6, lane = threadIdx.x & 63;
  int node = blockIdx.x * 4 + wave;
  if (node >= N) return;
  int f = lane * 2;
  unsigned int hh = *(const unsigned int*)(vhi + ((size_t)node << 7) + f);
  unsigned int ll = *(const unsigned int*)(vlo + ((size_t)node << 7) + f);
  vbuf[wave][f]     = bf2f((ushortT)hh)         + bf2f((ushortT)ll);
  vbuf[wave][f + 1] = bf2f((ushortT)(hh >> 16)) + bf2f((ushortT)(ll >> 16));
  float t0 = b1[lane], t1 = 0.f;        // split dependency chain
  #pragma unroll 8
  for (int k = 0; k < HDIM; k += 2){
    t0 = fmaf(vbuf[wave][k],     W1[k * 64 + lane],       t0);
    t1 = fmaf(vbuf[wave][k + 1], W1[(k + 1) * 64 + lane], t1);
  }
  float partial = ssp(t0 + t1) * W2[lane];
  #pragma unroll
  for (int off = 32; off > 0; off >>= 1)
    partial += __shfl_down(partial, off, 64);
  if (lane == 0)
    u[node] = partial + b2[0];
}

// ---------------- group segment sum over sorted batch ----------------
// groupOff[g] = first node index with batch >= g;  groupOff[G] = N
__global__ void k_bounds(const int* __restrict__ batch, int* __restrict__ groupOff,
                         int N, int G){
  int i = blockIdx.x * 256 + threadIdx.x;
  if (i >= N) return;
  int b = batch[i];
  if (i == 0){
    for (int g = 0; g <= b; ++g) groupOff[g] = 0;
  } else {
    int pb = batch[i - 1];
    for (int g = pb + 1; g <= b; ++g) groupOff[g] = i;
  }
  if (i == N - 1){
    for (int g = b + 1; g <= G; ++g) groupOff[g] = N;
  }
}

__global__ void k_gsum(const float* __restrict__ u, const int* __restrict__ groupOff,
                       float* __restrict__ out, int G){
  int g = blockIdx.x * 4 + (threadIdx.x >> 6);
  if (g >= G) return;
  int lane = threadIdx.x & 63;
  int s = groupOff[g], e = groupOff[g + 1];
  float acc = 0.f;
  for (int j = s + lane; j < e; j += 64) acc += u[j];
  #pragma unroll
  for (int off = 32; off > 0; off >>= 1)
    acc += __shfl_down(acc, off, 64);
  if (lane == 0) out[g] = acc;
}

extern "C" void kernel_launch(void* const* d_in, const int* in_sizes, int n_in,
                              void* d_out, int out_size, void* d_ws, size_t ws_size,
                              hipStream_t stream){
  const int N = in_sizes[0];
  const int E = in_sizes[3] / 2;
  const int G = out_size;

  const int*   z     = (const int*)d_in[0];
  const float* pos   = (const float*)d_in[1];
  const int*   batch = (const int*)d_in[2];
  const int*   eidx  = (const int*)d_in[3];
  const int*   erow  = eidx;
  const int*   ecol  = eidx + E;
  const float* emb   = (const float*)d_in[4];
  const float* dW    = (const float*)d_in[5];
  const float* db    = (const float*)d_in[6];
  const float* Wn    = (const float*)d_in[7];
  const float* We    = (const float*)d_in[8];
  const float* be    = (const float*)d_in[9];
  const float* Wo    = (const float*)d_in[10];
  const float* bo    = (const float*)d_in[11];
  const float* W1    = (const float*)d_in[12];
  const float* b1    = (const float*)d_in[13];
  const float* W2    = (const float*)d_in[14];
  const float* b2    = (const float*)d_in[15];

  char* ws = (char*)d_ws;
  size_t off = 0;
  auto alloc = [&](size_t bytes) -> char* {
    char* p = ws + off;
    off = (off + bytes + 255) & ~(size_t)255;
    return p;
  };
  int*     counts   = (int*)    alloc((size_t)N * 4);
  int*     offsets  = (int*)    alloc((size_t)(N + 1) * 4);
  int*     cursor   = (int*)    alloc((size_t)N * 4);
  int2*    csr_cd   = (int2*)   alloc((size_t)E * 8);
  ushortT* h        = (ushortT*)alloc((size_t)N * HDIM * 2);
  ushortT* vhi      = (ushortT*)alloc((size_t)N * HDIM * 2);
  ushortT* vlo      = (ushortT*)alloc((size_t)N * HDIM * 2);
  ushortT* agghi    = (ushortT*)alloc((size_t)N * HDIM * 2);
  ushortT* agglo    = (ushortT*)alloc((size_t)N * HDIM * 2);
  ushortT* WnHiT    = (ushortT*)alloc((size_t)NLAYER * HDIM * HDIM * 2);
  ushortT* WnLoT    = (ushortT*)alloc((size_t)NLAYER * HDIM * HDIM * 2);
  ushortT* WoHiT    = (ushortT*)alloc((size_t)NLAYER * HDIM * HDIM * 2);
  ushortT* WoLoT    = (ushortT*)alloc((size_t)NLAYER * HDIM * HDIM * 2);
  float*   a        = (float*)  alloc((size_t)NLAYER * HDIM * 4);
  float*   c        = (float*)  alloc((size_t)NLAYER * HDIM * 4);
  float*   u        = (float*)  alloc((size_t)N * 4);
  int*     groupOff = (int*)    alloc((size_t)(G + 1) * 4);

  hipMemsetAsync(counts, 0, (size_t)N * 4, stream);

  k_count<<<(E + 255) / 256, 256, 0, stream>>>(erow, counts, E);
  k_scan<<<1, 1024, 0, stream>>>(counts, offsets, cursor, N);
  k_fill<<<(E + 255) / 256, 256, 0, stream>>>(erow, ecol, pos, cursor, csr_cd, E);
  k_init_v<<<((size_t)N * HDIM + 255) / 256, 256, 0, stream>>>(z, emb, vhi, vlo, N);
  int wtotal = NLAYER * HDIM * HDIM;
  k_prepw<<<(wtotal + 255) / 256, 256, 0, stream>>>(Wn, WnHiT, WnLoT, wtotal);
  k_prepw<<<(wtotal + 255) / 256, 256, 0, stream>>>(Wo, WoHiT, WoLoT, wtotal);
  k_ac<<<(NLAYER * HDIM + 255) / 256, 256, 0, stream>>>(dW, db, We, be, a, c);
  k_bounds<<<(N + 255) / 256, 256, 0, stream>>>(batch, groupOff, N, G);

  int ntiles = (N + 15) >> 4;
  int gemmGrid = (ntiles + 7) / 8;        // 4 waves/block, 2 tiles/wave
  int nodeGrid = (N + 3) / 4;
  for (int l = 0; l < NLAYER; ++l){
    size_t wo = (size_t)l * HDIM * HDIM;
    k_gemm<0><<<gemmGrid, 256, 0, stream>>>(vhi, vlo, WnHiT + wo, WnLoT + wo,
                                            nullptr, h, nullptr, N);
    k_agg<<<nodeGrid, 256, 0, stream>>>(h, offsets, csr_cd,
                                        a + l * HDIM, c + l * HDIM, agghi, agglo, N);
    k_gemm<1><<<gemmGrid, 256, 0, stream>>>(agghi, agglo, WoHiT + wo, WoLoT + wo,
                                            bo + (size_t)l * HDIM, vhi, vlo, N);
  }
  k_readout<<<nodeGrid, 256, 0, stream>>>(vhi, vlo, W1, b1, W2, b2, u, N);
  k_gsum<<<(G + 3) / 4, 256, 0, stream>>>(u, groupOff, (float*)d_out, G);
}

// Round 5
// 1171.145 us; speedup vs baseline: 1.6378x; 1.0788x over previous
//
#include <hip/hip_runtime.h>
#include <math.h>

#define HDIM 128
#define NGAUSS 50
#define NLAYER 6

typedef unsigned short ushortT;
typedef __attribute__((ext_vector_type(8))) short bf16x8;
typedef __attribute__((ext_vector_type(4))) float f32x4;

static __device__ __forceinline__ float bf2f(unsigned short u){
  union { unsigned int i; float f; } x; x.i = ((unsigned int)u) << 16; return x.f;
}
static __device__ __forceinline__ unsigned short f2bf(float f){
  union { float f; unsigned int i; } x; x.f = f;
  unsigned int i = x.i;
  unsigned int r = (i + 0x7FFFu + ((i >> 16) & 1u)) >> 16;
  return (unsigned short)r;
}
// softplus(x) - log(2), numerically stable
static __device__ __forceinline__ float ssp(float x){
  float sp = fmaxf(x, 0.0f) + log1pf(expf(-fabsf(x)));
  return sp - 0.69314718055994530942f;
}

// ---------------- CSR build ----------------
__global__ void k_count(const int* __restrict__ row, int* __restrict__ counts, int E){
  int e = blockIdx.x * 256 + threadIdx.x;
  if (e < E) atomicAdd(&counts[row[e]], 1);
}

// 3-phase decoupled scan: blockSums -> scan blockSums -> per-block scan+offset
__global__ void k_scan1(const int* __restrict__ counts, int* __restrict__ blockSums, int N){
  __shared__ int red[256];
  int tid = threadIdx.x;
  int i = blockIdx.x * 256 + tid;
  red[tid] = (i < N) ? counts[i] : 0;
  __syncthreads();
  #pragma unroll
  for (int off = 128; off > 0; off >>= 1){
    if (tid < off) red[tid] += red[tid + off];
    __syncthreads();
  }
  if (tid == 0) blockSums[blockIdx.x] = red[0];
}

__global__ void k_scan2(const int* __restrict__ blockSums, int* __restrict__ blockOff, int nb){
  __shared__ int s[1024];
  int tid = threadIdx.x;
  s[tid] = (tid < nb) ? blockSums[tid] : 0;
  __syncthreads();
  for (int off = 1; off < 1024; off <<= 1){
    int t = (tid >= off) ? s[tid - off] : 0;
    __syncthreads();
    s[tid] += t;
    __syncthreads();
  }
  if (tid < nb) blockOff[tid] = (tid == 0) ? 0 : s[tid - 1];
}

__global__ void k_scan3(const int* __restrict__ counts, const int* __restrict__ blockOff,
                        int* __restrict__ offsets, int* __restrict__ cursor, int N){
  __shared__ int s[256];
  int tid = threadIdx.x;
  int i = blockIdx.x * 256 + tid;
  int v = (i < N) ? counts[i] : 0;
  s[tid] = v;
  __syncthreads();
  #pragma unroll
  for (int off = 1; off < 256; off <<= 1){
    int t = (tid >= off) ? s[tid - off] : 0;
    __syncthreads();
    s[tid] += t;
    __syncthreads();
  }
  int excl = blockOff[blockIdx.x] + s[tid] - v;
  if (i < N){ offsets[i] = excl; cursor[i] = excl; }
  if (i == N - 1) offsets[N] = excl + v;
}

// csr record: (col, dist-bits) packed as int2 -> one 8B store, one 8B load
__global__ void k_fill(const int* __restrict__ row, const int* __restrict__ col,
                       const float* __restrict__ pos, int* __restrict__ cursor,
                       int2* __restrict__ csr_cd, int E){
  int e = blockIdx.x * 256 + threadIdx.x;
  if (e >= E) return;
  int r = row[e], c = col[e];
  float dx = pos[r*3+0] - pos[c*3+0];
  float dy = pos[r*3+1] - pos[c*3+1];
  float dz = pos[r*3+2] - pos[c*3+2];
  float d = sqrtf(dx*dx + dy*dy + dz*dz);
  int slot = atomicAdd(&cursor[r], 1);
  csr_cd[slot] = make_int2(c, __float_as_int(d));
}

// ---------------- init / precompute ----------------
__global__ void k_init_v(const int* __restrict__ z, const float* __restrict__ emb,
                         ushortT* __restrict__ vhi, ushortT* __restrict__ vlo, int N){
  int idx = blockIdx.x * 256 + threadIdx.x;
  if (idx >= N * HDIM) return;
  int n = idx >> 7, f = idx & 127;
  float w = emb[z[n] * HDIM + f];
  unsigned short hi = f2bf(w);
  vhi[idx] = hi;
  vlo[idx] = f2bf(w - bf2f(hi));
}

// transpose + split weights: dst[mat][n][k] (hi/lo bf16) from src[mat][k][n] (f32)
__global__ void k_prepw(const float* __restrict__ W, ushortT* __restrict__ Whi,
                        ushortT* __restrict__ Wlo, int total){
  int idx = blockIdx.x * 256 + threadIdx.x;
  if (idx >= total) return;
  int mat = idx >> 14;           // / (128*128)
  int rem = idx & 16383;
  int n = rem >> 7, k = rem & 127;
  float w = W[(mat << 14) + k * HDIM + n];
  unsigned short hi = f2bf(w);
  Whi[idx] = hi;
  Wlo[idx] = f2bf(w - bf2f(hi));
}

// a[l][f] = sum_g dist_W[g]*We[l][g][f];  c[l][f] = sum_g dist_b[g]*We[l][g][f] + be[l][f]
__global__ void k_ac(const float* __restrict__ dW, const float* __restrict__ db,
                     const float* __restrict__ We, const float* __restrict__ be,
                     float* __restrict__ a, float* __restrict__ c){
  int idx = blockIdx.x * 256 + threadIdx.x;
  if (idx >= NLAYER * HDIM) return;
  int l = idx >> 7, f = idx & 127;
  float av = 0.f, cv = 0.f;
  for (int g = 0; g < NGAUSS; ++g){
    float we = We[(l * NGAUSS + g) * HDIM + f];
    av += dW[g] * we;
    cv += db[g] * we;
  }
  a[idx] = av;
  c[idx] = cv + be[idx];
}

// ---------------- 128x128 GEMM via MFMA, split precision, LDS-staged weights ----
// MODE 0: out = X @ W             -> outHi (bf16, hi only; feeds the gather)
// MODE 1: out = ssp(X @ W + b)    -> outHi/outLo (bf16 hi+lo split)
template<int MODE>
__global__ __launch_bounds__(256, 2)
void k_gemm(const ushortT* __restrict__ Xhi, const ushortT* __restrict__ Xlo,
            const ushortT* __restrict__ WhiT, const ushortT* __restrict__ WloT,
            const float* __restrict__ bias,
            ushortT* __restrict__ outHi, ushortT* __restrict__ outLo, int N){
  __shared__ ushortT lds[2 * 128 * 128];   // 64 KB exactly
  ushortT* lh = lds;
  ushortT* ll = lds + 128 * 128;
  int tid = threadIdx.x;
  #pragma unroll
  for (int i = 0; i < 8; ++i){
    int g = (i * 256 + tid) * 8;          // short index 0..16383, 8 contiguous
    int n = g >> 7, k = g & 127;
    int dst = n * 128 + ((k + 8 * (n & 15)) & 127);
    *(bf16x8*)(lh + dst) = *(const bf16x8*)(WhiT + g);
    *(bf16x8*)(ll + dst) = *(const bf16x8*)(WloT + g);
  }
  __syncthreads();

  int wave = tid >> 6, lane = tid & 63;
  int m = lane & 15, quad = lane >> 4;
  int ntiles = (N + 15) >> 4;
  for (int tile = blockIdx.x * 4 + wave; tile < ntiles; tile += gridDim.x * 4){
    int rowBase = tile << 4;
    int row = rowBase + m; if (row >= N) row = N - 1;
    bf16x8 ahi[4], alo[4];
    #pragma unroll
    for (int kk = 0; kk < 4; ++kk){
      ahi[kk] = *(const bf16x8*)(Xhi + ((size_t)row << 7) + kk*32 + quad*8);
      alo[kk] = *(const bf16x8*)(Xlo + ((size_t)row << 7) + kk*32 + quad*8);
    }
    #pragma unroll
    for (int ct = 0; ct < 8; ++ct){
      int ncol = ct * 16 + m;
      f32x4 d = {0.f, 0.f, 0.f, 0.f};
      #pragma unroll
      for (int kk = 0; kk < 4; ++kk){
        int koff = (kk*32 + quad*8 + 8*m) & 127;
        bf16x8 bh = *(const bf16x8*)(lh + ncol*128 + koff);
        bf16x8 bl = *(const bf16x8*)(ll + ncol*128 + koff);
        d = __builtin_amdgcn_mfma_f32_16x16x32_bf16(ahi[kk], bh, d, 0, 0, 0);
        d = __builtin_amdgcn_mfma_f32_16x16x32_bf16(ahi[kk], bl, d, 0, 0, 0);
        d = __builtin_amdgcn_mfma_f32_16x16x32_bf16(alo[kk], bh, d, 0, 0, 0);
      }
      #pragma unroll
      for (int r = 0; r < 4; ++r){
        int orow = rowBase + quad*4 + r;
        if (orow < N){
          if (MODE == 0){
            outHi[((size_t)orow << 7) + ncol] = f2bf(d[r]);
          } else {
            float s = ssp(d[r] + bias[ncol]);
            unsigned short hi = f2bf(s);
            outHi[((size_t)orow << 7) + ncol] = hi;
            outLo[((size_t)orow << 7) + ncol] = f2bf(s - bf2f(hi));
          }
        }
      }
    }
  }
}

// ---------------- edge aggregation: one wave per node, bf16 h, 8-edge MLP ----
__global__ void k_agg(const ushortT* __restrict__ h, const int* __restrict__ offsets,
                      const int2* __restrict__ cd, const float* __restrict__ a,
                      const float* __restrict__ c,
                      ushortT* __restrict__ aggHi, ushortT* __restrict__ aggLo, int N){
  int node = blockIdx.x * 4 + (threadIdx.x >> 6);
  if (node >= N) return;
  int lane = threadIdx.x & 63;
  int f = lane * 2;                       // this lane covers features f, f+1
  float a0 = a[f], a1 = a[f+1], c0 = c[f], c1 = c[f+1];
  int s = offsets[node], e = offsets[node + 1];
  float acc0 = 0.f, acc1 = 0.f;
  int j = s;
  // peel one edge if start is odd so int4 loads below are 16B-aligned
  if ((j & 1) && j < e){
    int2 q = cd[j];
    unsigned int p = *(const unsigned int*)(h + ((size_t)q.x << 7) + f);
    float dd = __int_as_float(q.y);
    acc0 = fmaf(bf2f((ushortT)p),          fmaf(dd, a0, c0), acc0);
    acc1 = fmaf(bf2f((ushortT)(p >> 16)),  fmaf(dd, a1, c1), acc1);
    ++j;
  }
  for (; j + 8 <= e; j += 8){
    int4 qa = *(const int4*)(cd + j);       // edges j, j+1
    int4 qb = *(const int4*)(cd + j + 2);
    int4 qc = *(const int4*)(cd + j + 4);
    int4 qd = *(const int4*)(cd + j + 6);
    unsigned int p0 = *(const unsigned int*)(h + ((size_t)qa.x << 7) + f);
    unsigned int p1 = *(const unsigned int*)(h + ((size_t)qa.z << 7) + f);
    unsigned int p2 = *(const unsigned int*)(h + ((size_t)qb.x << 7) + f);
    unsigned int p3 = *(const unsigned int*)(h + ((size_t)qb.z << 7) + f);
    unsigned int p4 = *(const unsigned int*)(h + ((size_t)qc.x << 7) + f);
    unsigned int p5 = *(const unsigned int*)(h + ((size_t)qc.z << 7) + f);
    unsigned int p6 = *(const unsigned int*)(h + ((size_t)qd.x << 7) + f);
    unsigned int p7 = *(const unsigned int*)(h + ((size_t)qd.z << 7) + f);
    float d0 = __int_as_float(qa.y), d1 = __int_as_float(qa.w);
    float d2 = __int_as_float(qb.y), d3 = __int_as_float(qb.w);
    float d4 = __int_as_float(qc.y), d5 = __int_as_float(qc.w);
    float d6 = __int_as_float(qd.y), d7 = __int_as_float(qd.w);
    acc0 = fmaf(bf2f((ushortT)p0),         fmaf(d0, a0, c0), acc0);
    acc1 = fmaf(bf2f((ushortT)(p0 >> 16)), fmaf(d0, a1, c1), acc1);
    acc0 = fmaf(bf2f((ushortT)p1),         fmaf(d1, a0, c0), acc0);
    acc1 = fmaf(bf2f((ushortT)(p1 >> 16)), fmaf(d1, a1, c1), acc1);
    acc0 = fmaf(bf2f((ushortT)p2),         fmaf(d2, a0, c0), acc0);
    acc1 = fmaf(bf2f((ushortT)(p2 >> 16)), fmaf(d2, a1, c1), acc1);
    acc0 = fmaf(bf2f((ushortT)p3),         fmaf(d3, a0, c0), acc0);
    acc1 = fmaf(bf2f((ushortT)(p3 >> 16)), fmaf(d3, a1, c1), acc1);
    acc0 = fmaf(bf2f((ushortT)p4),         fmaf(d4, a0, c0), acc0);
    acc1 = fmaf(bf2f((ushortT)(p4 >> 16)), fmaf(d4, a1, c1), acc1);
    acc0 = fmaf(bf2f((ushortT)p5),         fmaf(d5, a0, c0), acc0);
    acc1 = fmaf(bf2f((ushortT)(p5 >> 16)), fmaf(d5, a1, c1), acc1);
    acc0 = fmaf(bf2f((ushortT)p6),         fmaf(d6, a0, c0), acc0);
    acc1 = fmaf(bf2f((ushortT)(p6 >> 16)), fmaf(d6, a1, c1), acc1);
    acc0 = fmaf(bf2f((ushortT)p7),         fmaf(d7, a0, c0), acc0);
    acc1 = fmaf(bf2f((ushortT)(p7 >> 16)), fmaf(d7, a1, c1), acc1);
  }
  for (; j < e; ++j){
    int2 q = cd[j];
    unsigned int p = *(const unsigned int*)(h + ((size_t)q.x << 7) + f);
    float dd = __int_as_float(q.y);
    acc0 = fmaf(bf2f((ushortT)p),         fmaf(dd, a0, c0), acc0);
    acc1 = fmaf(bf2f((ushortT)(p >> 16)), fmaf(dd, a1, c1), acc1);
  }
  unsigned short h0 = f2bf(acc0), h1 = f2bf(acc1);
  size_t o = ((size_t)node << 7) + f;
  *(unsigned int*)(aggHi + o) = (unsigned int)h0 | ((unsigned int)h1 << 16);
  unsigned short l0 = f2bf(acc0 - bf2f(h0)), l1 = f2bf(acc1 - bf2f(h1));
  *(unsigned int*)(aggLo + o) = (unsigned int)l0 | ((unsigned int)l1 << 16);
}

// ---------------- readout: one wave per node, writes u[node] (no atomics) ----
__global__ void k_readout(const ushortT* __restrict__ vhi, const ushortT* __restrict__ vlo,
                          const float* __restrict__ W1, const float* __restrict__ b1,
                          const float* __restrict__ W2, const float* __restrict__ b2,
                          float* __restrict__ u, int N){
  __shared__ float vbuf[4][HDIM];
  int wave = threadIdx.x >> 6, lane = threadIdx.x & 63;
  int node = blockIdx.x * 4 + wave;
  if (node >= N) return;
  int f = lane * 2;
  unsigned int hh = *(const unsigned int*)(vhi + ((size_t)node << 7) + f);
  unsigned int ll = *(const unsigned int*)(vlo + ((size_t)node << 7) + f);
  vbuf[wave][f]     = bf2f((ushortT)hh)         + bf2f((ushortT)ll);
  vbuf[wave][f + 1] = bf2f((ushortT)(hh >> 16)) + bf2f((ushortT)(ll >> 16));
  float t0 = b1[lane], t1 = 0.f;        // split dependency chain
  #pragma unroll 8
  for (int k = 0; k < HDIM; k += 2){
    t0 = fmaf(vbuf[wave][k],     W1[k * 64 + lane],       t0);
    t1 = fmaf(vbuf[wave][k + 1], W1[(k + 1) * 64 + lane], t1);
  }
  float partial = ssp(t0 + t1) * W2[lane];
  #pragma unroll
  for (int off = 32; off > 0; off >>= 1)
    partial += __shfl_down(partial, off, 64);
  if (lane == 0)
    u[node] = partial + b2[0];
}

// ---------------- group segment sum over sorted batch ----------------
// groupOff[g] = first node index with batch >= g;  groupOff[G] = N
__global__ void k_bounds(const int* __restrict__ batch, int* __restrict__ groupOff,
                         int N, int G){
  int i = blockIdx.x * 256 + threadIdx.x;
  if (i >= N) return;
  int b = batch[i];
  if (i == 0){
    for (int g = 0; g <= b; ++g) groupOff[g] = 0;
  } else {
    int pb = batch[i - 1];
    for (int g = pb + 1; g <= b; ++g) groupOff[g] = i;
  }
  if (i == N - 1){
    for (int g = b + 1; g <= G; ++g) groupOff[g] = N;
  }
}

__global__ void k_gsum(const float* __restrict__ u, const int* __restrict__ groupOff,
                       float* __restrict__ out, int G){
  int g = blockIdx.x * 4 + (threadIdx.x >> 6);
  if (g >= G) return;
  int lane = threadIdx.x & 63;
  int s = groupOff[g], e = groupOff[g + 1];
  float acc = 0.f;
  for (int j = s + lane; j < e; j += 64) acc += u[j];
  #pragma unroll
  for (int off = 32; off > 0; off >>= 1)
    acc += __shfl_down(acc, off, 64);
  if (lane == 0) out[g] = acc;
}

extern "C" void kernel_launch(void* const* d_in, const int* in_sizes, int n_in,
                              void* d_out, int out_size, void* d_ws, size_t ws_size,
                              hipStream_t stream){
  const int N = in_sizes[0];
  const int E = in_sizes[3] / 2;
  const int G = out_size;

  const int*   z     = (const int*)d_in[0];
  const float* pos   = (const float*)d_in[1];
  const int*   batch = (const int*)d_in[2];
  const int*   eidx  = (const int*)d_in[3];
  const int*   erow  = eidx;
  const int*   ecol  = eidx + E;
  const float* emb   = (const float*)d_in[4];
  const float* dW    = (const float*)d_in[5];
  const float* db    = (const float*)d_in[6];
  const float* Wn    = (const float*)d_in[7];
  const float* We    = (const float*)d_in[8];
  const float* be    = (const float*)d_in[9];
  const float* Wo    = (const float*)d_in[10];
  const float* bo    = (const float*)d_in[11];
  const float* W1    = (const float*)d_in[12];
  const float* b1    = (const float*)d_in[13];
  const float* W2    = (const float*)d_in[14];
  const float* b2    = (const float*)d_in[15];

  char* ws = (char*)d_ws;
  size_t off = 0;
  auto alloc = [&](size_t bytes) -> char* {
    char* p = ws + off;
    off = (off + bytes + 255) & ~(size_t)255;
    return p;
  };
  int nscanb = (N + 255) / 256;
  int*     counts   = (int*)    alloc((size_t)N * 4);
  int*     offsets  = (int*)    alloc((size_t)(N + 1) * 4);
  int*     cursor   = (int*)    alloc((size_t)N * 4);
  int*     blockSums= (int*)    alloc((size_t)nscanb * 4);
  int*     blockOff = (int*)    alloc((size_t)nscanb * 4);
  int2*    csr_cd   = (int2*)   alloc((size_t)E * 8);
  ushortT* h        = (ushortT*)alloc((size_t)N * HDIM * 2);
  ushortT* vhi      = (ushortT*)alloc((size_t)N * HDIM * 2);
  ushortT* vlo      = (ushortT*)alloc((size_t)N * HDIM * 2);
  ushortT* agghi    = (ushortT*)alloc((size_t)N * HDIM * 2);
  ushortT* agglo    = (ushortT*)alloc((size_t)N * HDIM * 2);
  ushortT* WnHiT    = (ushortT*)alloc((size_t)NLAYER * HDIM * HDIM * 2);
  ushortT* WnLoT    = (ushortT*)alloc((size_t)NLAYER * HDIM * HDIM * 2);
  ushortT* WoHiT    = (ushortT*)alloc((size_t)NLAYER * HDIM * HDIM * 2);
  ushortT* WoLoT    = (ushortT*)alloc((size_t)NLAYER * HDIM * HDIM * 2);
  float*   a        = (float*)  alloc((size_t)NLAYER * HDIM * 4);
  float*   c        = (float*)  alloc((size_t)NLAYER * HDIM * 4);
  float*   u        = (float*)  alloc((size_t)N * 4);
  int*     groupOff = (int*)    alloc((size_t)(G + 1) * 4);

  hipMemsetAsync(counts, 0, (size_t)N * 4, stream);

  k_count<<<(E + 255) / 256, 256, 0, stream>>>(erow, counts, E);
  k_scan1<<<nscanb, 256, 0, stream>>>(counts, blockSums, N);
  k_scan2<<<1, 1024, 0, stream>>>(blockSums, blockOff, nscanb);
  k_scan3<<<nscanb, 256, 0, stream>>>(counts, blockOff, offsets, cursor, N);
  k_fill<<<(E + 255) / 256, 256, 0, stream>>>(erow, ecol, pos, cursor, csr_cd, E);
  k_init_v<<<((size_t)N * HDIM + 255) / 256, 256, 0, stream>>>(z, emb, vhi, vlo, N);
  int wtotal = NLAYER * HDIM * HDIM;
  k_prepw<<<(wtotal + 255) / 256, 256, 0, stream>>>(Wn, WnHiT, WnLoT, wtotal);
  k_prepw<<<(wtotal + 255) / 256, 256, 0, stream>>>(Wo, WoHiT, WoLoT, wtotal);
  k_ac<<<(NLAYER * HDIM + 255) / 256, 256, 0, stream>>>(dW, db, We, be, a, c);
  k_bounds<<<(N + 255) / 256, 256, 0, stream>>>(batch, groupOff, N, G);

  int ntiles = (N + 15) >> 4;
  int gemmGrid = (ntiles + 7) / 8;        // 4 waves/block, 2 tiles/wave
  int nodeGrid = (N + 3) / 4;
  for (int l = 0; l < NLAYER; ++l){
    size_t wo = (size_t)l * HDIM * HDIM;
    k_gemm<0><<<gemmGrid, 256, 0, stream>>>(vhi, vlo, WnHiT + wo, WnLoT + wo,
                                            nullptr, h, nullptr, N);
    k_agg<<<nodeGrid, 256, 0, stream>>>(h, offsets, csr_cd,
                                        a + l * HDIM, c + l * HDIM, agghi, agglo, N);
    k_gemm<1><<<gemmGrid, 256, 0, stream>>>(agghi, agglo, WoHiT + wo, WoLoT + wo,
                                            bo + (size_t)l * HDIM, vhi, vlo, N);
  }
  k_readout<<<nodeGrid, 256, 0, stream>>>(vhi, vlo, W1, b1, W2, b2, u, N);
  k_gsum<<<(G + 3) / 4, 256, 0, stream>>>(u, groupOff, (float*)d_out, G);
}